// Round 7
// baseline (1549.012 us; speedup 1.0000x reference)
//
#include <hip/hip_runtime.h>
#include <hip/hip_bf16.h>
#include <math.h>

// FraudGNN on MI355X. Edge-centric bucketed aggregation: counting-sort edges
// by (dst_bucket x src_half), then per-bucket LDS fp32 accumulators with the
// two src-half phases giving per-XCD-L2-resident gather tables (3.2 MB halves).
// Dense math stays in one fused MFMA kernel (H1 in LDS, G=H1@W2l pre-projected,
// S2=H1@W2r), FC+sigmoid fused into the layer-2 bucket kernel.

#define IN_C 64
#define HID 128
#define HID2 64
#define LDA 136      // LDS row stride for MFMA tiles
#define BRN 248      // dst-nodes per bucket (248*65*4 + 248*4 <= 64 KB LDS)
#define NBUCK 404    // ceil(100000/248)
#define NB2 808      // NBUCK * 2 (src halves)
#define P1B 256      // partition blocks

typedef short short8 __attribute__((ext_vector_type(8)));
typedef float f32x4 __attribute__((ext_vector_type(4)));
typedef float f32x2 __attribute__((ext_vector_type(2)));

__device__ inline unsigned short bfbits(float f) {
    __hip_bfloat16 h = __float2bfloat16(f);
    return *reinterpret_cast<unsigned short*>(&h);
}
__device__ inline float bflo(unsigned u) { return __uint_as_float(u << 16); }
__device__ inline float bfhi(unsigned u) { return __uint_as_float(u & 0xffff0000u); }
__device__ inline unsigned bfpack(float a, float b) {
    return ((unsigned)bfbits(b) << 16) | (unsigned)bfbits(a);
}
__device__ inline unsigned char f_to_fp8(float v) {
    return (unsigned char)(__builtin_amdgcn_cvt_pk_fp8_f32(v, v, 0, false) & 0xff);
}

// ---------------- k1: per-block (dst_bucket x src_half) histogram ------------
// Also folds x -> fp8 conversion (independent work).
__global__ __launch_bounds__(256) void count_kernel(
    const int* __restrict__ ei, int* __restrict__ cnt,
    const float4* __restrict__ x4, unsigned* __restrict__ xf8,
    int n4, int E, int EPB, int halfN)
{
    __shared__ int hist[NB2];
    int t = threadIdx.x, j = blockIdx.x;
    for (int i = t; i < NB2; i += 256) hist[i] = 0;
    __syncthreads();
    int e0 = j * EPB, e1 = min(e0 + EPB, E);
    for (int e = e0 + t; e < e1; e += 256) {
        int s = ei[e], d = ei[E + e];
        int b = ((unsigned)d / BRN) * 2 + (s >= halfN);
        atomicAdd(&hist[b], 1);
    }
    for (int i = j * 256 + t; i < n4; i += P1B * 256) {
        float4 f = x4[i];
        int lo = __builtin_amdgcn_cvt_pk_fp8_f32(f.x, f.y, 0, false);
        xf8[i] = (unsigned)__builtin_amdgcn_cvt_pk_fp8_f32(f.z, f.w, lo, true);
    }
    __syncthreads();
    for (int i = t; i < NB2; i += 256) cnt[j * NB2 + i] = hist[i];
}

// ---------------- k2: bucket bases + per-block scatter offsets ---------------
__global__ __launch_bounds__(256) void offs_kernel(
    const int* __restrict__ cnt, int* __restrict__ gofs,
    int* __restrict__ bucket_base, int E)
{
    __shared__ int tot[1024];
    int t = threadIdx.x;
    for (int c = t; c < 1024; c += 256) tot[c] = 0;
    __syncthreads();
    for (int c = t; c < NB2; c += 256) {
        int run = 0;
        for (int j = 0; j < P1B; ++j) run += cnt[j * NB2 + c]; // coalesced per j
        tot[c] = run;
    }
    __syncthreads();
    for (int off = 1; off < 1024; off <<= 1) {
        int v0 = (t >= off) ? tot[t - off] : 0;
        int v1 = (t + 256 >= off) ? tot[t + 256 - off] : 0;
        int v2 = (t + 512 >= off) ? tot[t + 512 - off] : 0;
        int v3 = (t + 768 >= off) ? tot[t + 768 - off] : 0;
        __syncthreads();
        tot[t] += v0; tot[t + 256] += v1; tot[t + 512] += v2; tot[t + 768] += v3;
        __syncthreads();
    }
    for (int c = t; c < NB2; c += 256) {
        int bb = (c == 0) ? 0 : tot[c - 1];       // exclusive bucket base
        bucket_base[c] = bb;
        int run = bb;
        for (int j = 0; j < P1B; ++j) {
            gofs[j * NB2 + c] = run;              // coalesced per j
            run += cnt[j * NB2 + c];
        }
    }
    if (t == 0) bucket_base[NB2] = E;
}

// ---------------- k3: scatter packed (src<<8 | dst_local) --------------------
__global__ __launch_bounds__(256) void scatter_kernel(
    const int* __restrict__ ei, const int* __restrict__ gofs,
    int* __restrict__ part, int E, int EPB, int halfN)
{
    __shared__ int lofs[NB2];
    int t = threadIdx.x, j = blockIdx.x;
    for (int i = t; i < NB2; i += 256) lofs[i] = gofs[j * NB2 + i];
    __syncthreads();
    int e0 = j * EPB, e1 = min(e0 + EPB, E);
    for (int e = e0 + t; e < e1; e += 256) {
        int s = ei[e], d = ei[E + e];
        unsigned db = (unsigned)d / BRN;
        int b = db * 2 + (s >= halfN);
        int dl = d - (int)db * BRN;
        int p = atomicAdd(&lofs[b], 1);
        part[p] = (s << 8) | dl;
    }
}

// ---------------- k4: bucket aggregate of x(fp8) -> M1 (bf16) ---------------
// One block per dst-bucket; 248x64 fp32 accumulators in LDS; two src-half
// phases (blocks co-resident & uniform => phase-aligned => L2-resident table).
__global__ __launch_bounds__(512) void bagg1_kernel(
    const int* __restrict__ part, const int* __restrict__ bucket_base,
    const unsigned* __restrict__ xf8, unsigned* __restrict__ M1u, int N)
{
    __shared__ float acc[BRN * 65];
    __shared__ int ndeg[BRN];
    int t = threadIdx.x, b = blockIdx.x;
    int node0 = b * BRN;
    for (int i = t; i < BRN * 65; i += 512) acc[i] = 0.f;
    if (t < BRN) ndeg[t] = 0;
    __syncthreads();
    int qw = t >> 4, ql = t & 15;
    for (int ph = 0; ph < 2; ++ph) {
        int g0 = bucket_base[2 * b + ph], g1 = bucket_base[2 * b + ph + 1];
        for (int i0 = g0 + qw * 8; i0 < g1; i0 += 256) {
#pragma unroll
            for (int u = 0; u < 8; ++u) {
                int i = i0 + u;
                bool v = i < g1;
                int p = part[v ? i : g0];
                int s = ((unsigned)p) >> 8, dl = p & 255;
                unsigned gx = xf8[s * 16 + ql];
                if (v) {
                    f32x2 lo = __builtin_amdgcn_cvt_pk_f32_fp8((int)gx, false);
                    f32x2 hi = __builtin_amdgcn_cvt_pk_f32_fp8((int)gx, true);
                    atomicAdd(&acc[dl * 65 + 4 * ql + 0], lo[0]);
                    atomicAdd(&acc[dl * 65 + 4 * ql + 1], lo[1]);
                    atomicAdd(&acc[dl * 65 + 4 * ql + 2], hi[0]);
                    atomicAdd(&acc[dl * 65 + 4 * ql + 3], hi[1]);
                    if (ql == 0) atomicAdd(&ndeg[dl], 1);
                }
            }
        }
        __syncthreads();
    }
    for (int idx = t; idx < BRN * 16; idx += 512) {
        int n = idx >> 4, g = idx & 15;
        int node = node0 + n;
        if (node < N) {
            int dg = ndeg[n];
            float sc = dg > 0 ? 1.f / (float)dg : 0.f;
            float f0 = acc[n * 65 + 4 * g + 0] * sc;
            float f1 = acc[n * 65 + 4 * g + 1] * sc;
            float f2 = acc[n * 65 + 4 * g + 2] * sc;
            float f3 = acc[n * 65 + 4 * g + 3] * sc;
            uint2 P;
            P.x = bfpack(f0, f1);
            P.y = bfpack(f2, f3);
            ((uint2*)M1u)[(size_t)node * 16 + g] = P;
        }
    }
}

// ---------------- fused dense: H1 -> G (fp8), S2 (bf16) ----------------
__global__ __launch_bounds__(256) void dense_kernel(
    const unsigned short* __restrict__ M1s, const float* __restrict__ x,
    const float* __restrict__ W1l, const float* __restrict__ b1,
    const float* __restrict__ W1r, const float* __restrict__ W2l,
    const float* __restrict__ W2r, unsigned* __restrict__ G8,
    unsigned* __restrict__ S2u, int N)
{
    __shared__ unsigned short sA[128 * LDA];
    __shared__ unsigned short sB[128 * LDA];
    int tid = threadIdx.x;
    int base = blockIdx.x * 128;

    for (int i = tid; i < 128 * 128; i += 256) {
        int k = i >> 7, n = i & 127;
        float wv = (k < 64) ? W1l[k * HID + n] : W1r[(k - 64) * HID + n];
        sB[n * LDA + k] = bfbits(wv);
    }
    for (int i = tid; i < 128 * 64; i += 256) {
        int r = i >> 6, c = i & 63;
        int node = min(base + r, N - 1);
        sA[r * LDA + c] = M1s[(size_t)node * 64 + c];
        sA[r * LDA + 64 + c] = bfbits(x[(size_t)node * 64 + c]);
    }
    __syncthreads();

    int w = tid >> 6, lane = tid & 63;
    int m0 = w * 32;
    int mr = lane & 15, q = lane >> 4;
    const f32x4 zero = {0.f, 0.f, 0.f, 0.f};

    f32x4 acc[2][8];
#pragma unroll
    for (int mt = 0; mt < 2; ++mt)
#pragma unroll
        for (int nt = 0; nt < 8; ++nt) acc[mt][nt] = zero;

#pragma unroll
    for (int kt = 0; kt < 4; ++kt) {
        short8 a0 = *reinterpret_cast<const short8*>(&sA[(m0 + mr) * LDA + kt * 32 + q * 8]);
        short8 a1 = *reinterpret_cast<const short8*>(&sA[(m0 + 16 + mr) * LDA + kt * 32 + q * 8]);
#pragma unroll
        for (int nt = 0; nt < 8; ++nt) {
            short8 b = *reinterpret_cast<const short8*>(&sB[(nt * 16 + mr) * LDA + kt * 32 + q * 8]);
            acc[0][nt] = __builtin_amdgcn_mfma_f32_16x16x32_bf16(a0, b, acc[0][nt], 0, 0, 0);
            acc[1][nt] = __builtin_amdgcn_mfma_f32_16x16x32_bf16(a1, b, acc[1][nt], 0, 0, 0);
        }
    }
    __syncthreads();

#pragma unroll
    for (int mt = 0; mt < 2; ++mt)
#pragma unroll
        for (int nt = 0; nt < 8; ++nt)
#pragma unroll
            for (int j = 0; j < 4; ++j) {
                int row = m0 + mt * 16 + q * 4 + j;
                int col = nt * 16 + mr;
                float v = acc[mt][nt][j] + b1[col];
                sA[row * LDA + col] = bfbits(fmaxf(v, 0.f));
            }
    for (int i = tid; i < 128 * 128; i += 256) {
        int c = i >> 7, n = i & 127;
        float wv = (n < 64) ? W2l[c * HID2 + n] : W2r[c * HID2 + (n - 64)];
        sB[n * LDA + c] = bfbits(wv);
    }
    __syncthreads();

    f32x4 acc2[2][8];
#pragma unroll
    for (int mt = 0; mt < 2; ++mt)
#pragma unroll
        for (int nt = 0; nt < 8; ++nt) acc2[mt][nt] = zero;

#pragma unroll
    for (int kt = 0; kt < 4; ++kt) {
        short8 a0 = *reinterpret_cast<const short8*>(&sA[(m0 + mr) * LDA + kt * 32 + q * 8]);
        short8 a1 = *reinterpret_cast<const short8*>(&sA[(m0 + 16 + mr) * LDA + kt * 32 + q * 8]);
#pragma unroll
        for (int nt = 0; nt < 8; ++nt) {
            short8 b = *reinterpret_cast<const short8*>(&sB[(nt * 16 + mr) * LDA + kt * 32 + q * 8]);
            acc2[0][nt] = __builtin_amdgcn_mfma_f32_16x16x32_bf16(a0, b, acc2[0][nt], 0, 0, 0);
            acc2[1][nt] = __builtin_amdgcn_mfma_f32_16x16x32_bf16(a1, b, acc2[1][nt], 0, 0, 0);
        }
    }
    __syncthreads(); // stage-2 LDS reads done; reuse sA/sB as output staging

    unsigned char* sG = (unsigned char*)sA;     // [128][64] fp8
    unsigned short* sS = (unsigned short*)sB;   // [128][64] bf16
#pragma unroll
    for (int mt = 0; mt < 2; ++mt)
#pragma unroll
        for (int nt = 0; nt < 8; ++nt)
#pragma unroll
            for (int j = 0; j < 4; ++j) {
                int row = m0 + mt * 16 + q * 4 + j;
                int col = nt * 16 + mr;
                float v = acc2[mt][nt][j];
                if (col < 64) sG[row * 64 + col] = f_to_fp8(v);
                else          sS[row * 64 + (col - 64)] = bfbits(v);
            }
    __syncthreads();
    const unsigned* sGu = (const unsigned*)sG;
    for (int i = tid; i < 128 * 16; i += 256) {
        int r = i >> 4, node = base + r;
        if (node < N) G8[(size_t)node * 16 + (i & 15)] = sGu[i];
    }
    const unsigned* sSu = (const unsigned*)sS;
    for (int i = tid; i < 128 * 32; i += 256) {
        int r = i >> 5, node = base + r;
        if (node < N) S2u[(size_t)node * 32 + (i & 31)] = sSu[i];
    }
}

// ---------------- k6: bucket aggregate of G(fp8) + FC + sigmoid --------------
__global__ __launch_bounds__(512) void bagg2fc_kernel(
    const int* __restrict__ part, const int* __restrict__ bucket_base,
    const unsigned* __restrict__ G8, const unsigned* __restrict__ S2u,
    const float* __restrict__ b2, const float* __restrict__ Wfc,
    const float* __restrict__ bfc, float* __restrict__ out, int N)
{
    __shared__ float acc[BRN * 65];
    __shared__ int ndeg[BRN];
    int t = threadIdx.x, b = blockIdx.x;
    int node0 = b * BRN;
    for (int i = t; i < BRN * 65; i += 512) acc[i] = 0.f;
    if (t < BRN) ndeg[t] = 0;
    __syncthreads();
    int qw = t >> 4, ql = t & 15;
    for (int ph = 0; ph < 2; ++ph) {
        int g0 = bucket_base[2 * b + ph], g1 = bucket_base[2 * b + ph + 1];
        for (int i0 = g0 + qw * 8; i0 < g1; i0 += 256) {
#pragma unroll
            for (int u = 0; u < 8; ++u) {
                int i = i0 + u;
                bool v = i < g1;
                int p = part[v ? i : g0];
                int s = ((unsigned)p) >> 8, dl = p & 255;
                unsigned gx = G8[s * 16 + ql];
                if (v) {
                    f32x2 lo = __builtin_amdgcn_cvt_pk_f32_fp8((int)gx, false);
                    f32x2 hi = __builtin_amdgcn_cvt_pk_f32_fp8((int)gx, true);
                    atomicAdd(&acc[dl * 65 + 4 * ql + 0], lo[0]);
                    atomicAdd(&acc[dl * 65 + 4 * ql + 1], lo[1]);
                    atomicAdd(&acc[dl * 65 + 4 * ql + 2], hi[0]);
                    atomicAdd(&acc[dl * 65 + 4 * ql + 3], hi[1]);
                    if (ql == 0) atomicAdd(&ndeg[dl], 1);
                }
            }
        }
        __syncthreads();
    }
    // finalize: z = sum_j relu(mean_j + S2_j + b2_j) * Wfc_j ; sigmoid
    for (int iter = 0; iter < 8; ++iter) {
        int n = qw + 32 * iter;
        int node = node0 + n;
        if (n < BRN && node < N) {
            int dg = ndeg[n];
            float sc = dg > 0 ? 1.f / (float)dg : 0.f;
            uint2 s2 = ((const uint2*)S2u)[(size_t)node * 16 + ql];
            int c0 = 4 * ql;
            float z = fmaxf(acc[n * 65 + c0 + 0] * sc + bflo(s2.x) + b2[c0 + 0], 0.f) * Wfc[c0 + 0]
                    + fmaxf(acc[n * 65 + c0 + 1] * sc + bfhi(s2.x) + b2[c0 + 1], 0.f) * Wfc[c0 + 1]
                    + fmaxf(acc[n * 65 + c0 + 2] * sc + bflo(s2.y) + b2[c0 + 2], 0.f) * Wfc[c0 + 2]
                    + fmaxf(acc[n * 65 + c0 + 3] * sc + bfhi(s2.y) + b2[c0 + 3], 0.f) * Wfc[c0 + 3];
            z += __shfl_xor(z, 1); z += __shfl_xor(z, 2);
            z += __shfl_xor(z, 4); z += __shfl_xor(z, 8);
            if (ql == 0) out[node] = 1.f / (1.f + __expf(-(z + bfc[0])));
        }
    }
}

// ---------------- launch ----------------
static inline size_t align_up(size_t v, size_t a) { return (v + a - 1) & ~(a - 1); }

extern "C" void kernel_launch(void* const* d_in, const int* in_sizes, int n_in,
                              void* d_out, int out_size, void* d_ws, size_t ws_size,
                              hipStream_t stream) {
    const float* x   = (const float*)d_in[0];
    const int*   ei  = (const int*)d_in[1];
    const float* W1l = (const float*)d_in[2];
    const float* b1  = (const float*)d_in[3];
    const float* W1r = (const float*)d_in[4];
    const float* W2l = (const float*)d_in[5];
    const float* b2  = (const float*)d_in[6];
    const float* W2r = (const float*)d_in[7];
    const float* Wfc = (const float*)d_in[8];
    const float* bfc = (const float*)d_in[9];
    float* out = (float*)d_out;

    const int N = in_sizes[0] / IN_C;   // 100000
    const int E = in_sizes[1] / 2;      // 1600000
    const int EPB = (E + P1B - 1) / P1B;
    const int halfN = N >> 1;

    char* ws = (char*)d_ws;
    size_t o = 0;
    int* cnt  = (int*)(ws + o); o = align_up(o + (size_t)P1B * NB2 * 4, 256);
    int* gofs = (int*)(ws + o); o = align_up(o + (size_t)P1B * NB2 * 4, 256);
    int* bb   = (int*)(ws + o); o = align_up(o + (size_t)(NB2 + 1) * 4, 256);
    int* part = (int*)(ws + o); o = align_up(o + (size_t)E * 4, 256);
    unsigned* xf8 = (unsigned*)(ws + o); o = align_up(o + (size_t)N * 16 * 4, 256);
    unsigned* M1u = (unsigned*)(ws + o); o = align_up(o + (size_t)N * 32 * 4, 256);
    unsigned* S2u = (unsigned*)(ws + o); o = align_up(o + (size_t)N * 32 * 4, 256);
    unsigned* G8  = (unsigned*)(ws + o); o = align_up(o + (size_t)N * 16 * 4, 256);

    count_kernel<<<P1B, 256, 0, stream>>>(ei, cnt, (const float4*)x, xf8,
                                          N * 16, E, EPB, halfN);
    offs_kernel<<<1, 256, 0, stream>>>(cnt, gofs, bb, E);
    scatter_kernel<<<P1B, 256, 0, stream>>>(ei, gofs, part, E, EPB, halfN);
    bagg1_kernel<<<NBUCK, 512, 0, stream>>>(part, bb, xf8, M1u, N);
    dense_kernel<<<(N + 127) / 128, 256, 0, stream>>>(
        (const unsigned short*)M1u, x, W1l, b1, W1r, W2l, W2r, G8, S2u, N);
    bagg2fc_kernel<<<NBUCK, 512, 0, stream>>>(part, bb, G8, S2u, b2, Wfc, bfc, out, N);
}

// Round 8
// 356.407 us; speedup vs baseline: 4.3462x; 4.3462x over previous
//
#include <hip/hip_runtime.h>
#include <hip/hip_bf16.h>
#include <math.h>

// FraudGNN on MI355X. R6 structure (counting-sort CSR, fp8 gather tables,
// fused MFMA dense) + wide-load aggs: 4 lanes x dwordx4 per edge row = 16
// edges per wave load instruction, shfl_xor reduction tree. NO LDS atomics
// (R7 post-mortem: 102M ds-atomics/layer = 670 us/layer).

#define IN_C 64
#define HID 128
#define HID2 64
#define LDA 136     // LDS row stride for MFMA tiles
#define NBSHIFT 9   // 512 nodes per bucket
#define BR 512
#define P1B 256     // partition blocks (needs NBUCK <= 256: N <= 131072)

typedef short short8 __attribute__((ext_vector_type(8)));
typedef float f32x4 __attribute__((ext_vector_type(4)));
typedef float f32x2 __attribute__((ext_vector_type(2)));

__device__ inline unsigned short bfbits(float f) {
    __hip_bfloat16 h = __float2bfloat16(f);
    return *reinterpret_cast<unsigned short*>(&h);
}
__device__ inline float bflo(unsigned u) { return __uint_as_float(u << 16); }
__device__ inline float bfhi(unsigned u) { return __uint_as_float(u & 0xffff0000u); }
__device__ inline unsigned bfpack(float a, float b) {
    return ((unsigned)bfbits(b) << 16) | (unsigned)bfbits(a);
}
__device__ inline unsigned char f_to_fp8(float v) {
    return (unsigned char)(__builtin_amdgcn_cvt_pk_fp8_f32(v, v, 0, false) & 0xff);
}

// ---------------- CSR build: counting sort, bucket-contiguous ----------------
__global__ __launch_bounds__(256) void count_kernel(
    const int* __restrict__ ei, int* __restrict__ cnt,
    const float4* __restrict__ x4, unsigned* __restrict__ xf8,
    int n4, int E, int EPB, int NBUCK)
{
    __shared__ int hist[256];
    int t = threadIdx.x, j = blockIdx.x;
    hist[t] = 0;
    __syncthreads();
    int e0 = j * EPB, e1 = min(e0 + EPB, E);
    for (int e = e0 + t; e < e1; e += 256)
        atomicAdd(&hist[ei[E + e] >> NBSHIFT], 1);
    for (int i = j * 256 + t; i < n4; i += P1B * 256) {
        float4 f = x4[i];
        int lo = __builtin_amdgcn_cvt_pk_fp8_f32(f.x, f.y, 0, false);
        xf8[i] = (unsigned)__builtin_amdgcn_cvt_pk_fp8_f32(f.z, f.w, lo, true);
    }
    __syncthreads();
    if (t < NBUCK) cnt[j * NBUCK + t] = hist[t];
}

__global__ __launch_bounds__(256) void offs_kernel(
    const int* __restrict__ cnt, int* __restrict__ gofs,
    int* __restrict__ bucket_base, int* __restrict__ row_ptr,
    int N, int E, int NBUCK)
{
    __shared__ int tot[256];
    __shared__ int wred[4];
    int t = threadIdx.x, lane = t & 63, w = t >> 6;
    int run = 0;
    for (int j = 0; j < P1B; ++j)
        run += (t < NBUCK) ? cnt[j * NBUCK + t] : 0;
    tot[t] = run;
    __syncthreads();
    int v = tot[t];
    int x = v;
    for (int off = 1; off < 64; off <<= 1) {
        int u = __shfl_up(x, off);
        if (lane >= off) x += u;
    }
    if (lane == 63) wred[w] = x;
    __syncthreads();
    int add = 0;
    for (int k = 0; k < w; ++k) add += wred[k];
    int bb = x + add - v;
    if (t < NBUCK) bucket_base[t] = bb;
    if (t == 0) { bucket_base[NBUCK] = E; row_ptr[N] = E; }
    int run2 = bb;
    for (int j = 0; j < P1B; ++j) {
        if (t < NBUCK) {
            gofs[j * NBUCK + t] = run2;
            run2 += cnt[j * NBUCK + t];
        }
    }
}

__global__ __launch_bounds__(256) void scatter_kernel(
    const int* __restrict__ ei, const int* __restrict__ gofs,
    int2* __restrict__ part, int E, int EPB, int NBUCK)
{
    __shared__ int lofs[256];
    int t = threadIdx.x, j = blockIdx.x;
    lofs[t] = (t < NBUCK) ? gofs[j * NBUCK + t] : 0;
    __syncthreads();
    int e0 = j * EPB, e1 = min(e0 + EPB, E);
    for (int e = e0 + t; e < e1; e += 256) {
        int s = ei[e], d = ei[E + e];
        int p = atomicAdd(&lofs[d >> NBSHIFT], 1);
        part[p] = make_int2(s, d);
    }
}

__global__ __launch_bounds__(256) void csr_kernel(
    const int2* __restrict__ part, const int* __restrict__ bucket_base,
    int* __restrict__ row_ptr, int* __restrict__ srcs, int N)
{
    __shared__ int ncnt[BR];
    __shared__ int nofs[BR];
    __shared__ int nfill[BR];
    __shared__ int wred[4];
    int b = blockIdx.x;
    int t = threadIdx.x, lane = t & 63, w = t >> 6;
    int node0 = b << NBSHIFT;
    int nn = min(BR, N - node0);
    int gb0 = bucket_base[b], gb1 = bucket_base[b + 1];
    ncnt[t] = 0; ncnt[t + 256] = 0;
    __syncthreads();
    for (int i = gb0 + t; i < gb1; i += 256)
        atomicAdd(&ncnt[part[i].y - node0], 1);
    __syncthreads();
    int c0 = ncnt[2 * t], c1 = ncnt[2 * t + 1];
    int v = c0 + c1;
    int x = v;
    for (int off = 1; off < 64; off <<= 1) {
        int u = __shfl_up(x, off);
        if (lane >= off) x += u;
    }
    if (lane == 63) wred[w] = x;
    __syncthreads();
    int add = 0;
    for (int k = 0; k < w; ++k) add += wred[k];
    int exc = x + add - v;
    nofs[2 * t] = exc;          nofs[2 * t + 1] = exc + c0;
    nfill[2 * t] = exc;         nfill[2 * t + 1] = exc + c0;
    __syncthreads();
    for (int i = t; i < nn; i += 256) row_ptr[node0 + i] = gb0 + nofs[i];
    for (int i = gb0 + t; i < gb1; i += 256) {
        int2 p = part[i];
        int pos = atomicAdd(&nfill[p.y - node0], 1);
        srcs[gb0 + pos] = p.x;
    }
}

// ---------------- gather-mean of x(fp8) -> M1 (bf16) ----------------
// Wave per node; 4 lanes x 16B per edge row => 16 edges per load instruction,
// 1 KB outstanding per wave. shfl_xor tree over lane bits 2..5.
__global__ __launch_bounds__(256) void agg1_kernel(
    const unsigned* __restrict__ xf8, const int* __restrict__ row_ptr,
    const int* __restrict__ srcs, unsigned* __restrict__ M1u, int N)
{
    int g = blockIdx.x * 256 + threadIdx.x;
    int node = g >> 6;
    if (node >= N) return;
    int lane = g & 63, el = lane >> 2, p = lane & 3;
    int s0 = row_ptr[node], s1 = row_ptr[node + 1];
    float a[16];
#pragma unroll
    for (int j = 0; j < 16; ++j) a[j] = 0.f;
    for (int e = s0; e < s1; e += 16) {
        int ek = e + el;
        bool valid = ek < s1;
        int src = srcs[valid ? ek : s0];
        uint4 u = ((const uint4*)(xf8 + (size_t)src * 16))[p];
        if (valid) {
            f32x2 l0 = __builtin_amdgcn_cvt_pk_f32_fp8((int)u.x, false);
            f32x2 h0 = __builtin_amdgcn_cvt_pk_f32_fp8((int)u.x, true);
            f32x2 l1 = __builtin_amdgcn_cvt_pk_f32_fp8((int)u.y, false);
            f32x2 h1 = __builtin_amdgcn_cvt_pk_f32_fp8((int)u.y, true);
            f32x2 l2 = __builtin_amdgcn_cvt_pk_f32_fp8((int)u.z, false);
            f32x2 h2 = __builtin_amdgcn_cvt_pk_f32_fp8((int)u.z, true);
            f32x2 l3 = __builtin_amdgcn_cvt_pk_f32_fp8((int)u.w, false);
            f32x2 h3 = __builtin_amdgcn_cvt_pk_f32_fp8((int)u.w, true);
            a[0] += l0[0];  a[1] += l0[1];  a[2] += h0[0];  a[3] += h0[1];
            a[4] += l1[0];  a[5] += l1[1];  a[6] += h1[0];  a[7] += h1[1];
            a[8] += l2[0];  a[9] += l2[1];  a[10] += h2[0]; a[11] += h2[1];
            a[12] += l3[0]; a[13] += l3[1]; a[14] += h3[0]; a[15] += h3[1];
        }
    }
#pragma unroll
    for (int off = 4; off <= 32; off <<= 1)
#pragma unroll
        for (int j = 0; j < 16; ++j) a[j] += __shfl_xor(a[j], off);
    int deg = s1 - s0;
    float sc = deg > 0 ? 1.f / (float)deg : 0.f;
    if (el == 0) {
        uint4 o0, o1;
        o0.x = bfpack(a[0] * sc, a[1] * sc);
        o0.y = bfpack(a[2] * sc, a[3] * sc);
        o0.z = bfpack(a[4] * sc, a[5] * sc);
        o0.w = bfpack(a[6] * sc, a[7] * sc);
        o1.x = bfpack(a[8] * sc, a[9] * sc);
        o1.y = bfpack(a[10] * sc, a[11] * sc);
        o1.z = bfpack(a[12] * sc, a[13] * sc);
        o1.w = bfpack(a[14] * sc, a[15] * sc);
        ((uint4*)(M1u + (size_t)node * 32))[2 * p] = o0;
        ((uint4*)(M1u + (size_t)node * 32))[2 * p + 1] = o1;
    }
}

// ---------------- fused dense: H1 -> G (fp8), S2 (bf16) ----------------
__global__ __launch_bounds__(256) void dense_kernel(
    const unsigned short* __restrict__ M1s, const float* __restrict__ x,
    const float* __restrict__ W1l, const float* __restrict__ b1,
    const float* __restrict__ W1r, const float* __restrict__ W2l,
    const float* __restrict__ W2r, unsigned* __restrict__ G8,
    unsigned* __restrict__ S2u, int N)
{
    __shared__ unsigned short sA[128 * LDA];
    __shared__ unsigned short sB[128 * LDA];
    int tid = threadIdx.x;
    int base = blockIdx.x * 128;

    for (int i = tid; i < 128 * 128; i += 256) {
        int k = i >> 7, n = i & 127;
        float wv = (k < 64) ? W1l[k * HID + n] : W1r[(k - 64) * HID + n];
        sB[n * LDA + k] = bfbits(wv);
    }
    for (int i = tid; i < 128 * 64; i += 256) {
        int r = i >> 6, c = i & 63;
        int node = min(base + r, N - 1);
        sA[r * LDA + c] = M1s[(size_t)node * 64 + c];
        sA[r * LDA + 64 + c] = bfbits(x[(size_t)node * 64 + c]);
    }
    __syncthreads();

    int w = tid >> 6, lane = tid & 63;
    int m0 = w * 32;
    int mr = lane & 15, q = lane >> 4;
    const f32x4 zero = {0.f, 0.f, 0.f, 0.f};

    f32x4 acc[2][8];
#pragma unroll
    for (int mt = 0; mt < 2; ++mt)
#pragma unroll
        for (int nt = 0; nt < 8; ++nt) acc[mt][nt] = zero;

#pragma unroll
    for (int kt = 0; kt < 4; ++kt) {
        short8 a0 = *reinterpret_cast<const short8*>(&sA[(m0 + mr) * LDA + kt * 32 + q * 8]);
        short8 a1 = *reinterpret_cast<const short8*>(&sA[(m0 + 16 + mr) * LDA + kt * 32 + q * 8]);
#pragma unroll
        for (int nt = 0; nt < 8; ++nt) {
            short8 b = *reinterpret_cast<const short8*>(&sB[(nt * 16 + mr) * LDA + kt * 32 + q * 8]);
            acc[0][nt] = __builtin_amdgcn_mfma_f32_16x16x32_bf16(a0, b, acc[0][nt], 0, 0, 0);
            acc[1][nt] = __builtin_amdgcn_mfma_f32_16x16x32_bf16(a1, b, acc[1][nt], 0, 0, 0);
        }
    }
    __syncthreads();

#pragma unroll
    for (int mt = 0; mt < 2; ++mt)
#pragma unroll
        for (int nt = 0; nt < 8; ++nt)
#pragma unroll
            for (int j = 0; j < 4; ++j) {
                int row = m0 + mt * 16 + q * 4 + j;
                int col = nt * 16 + mr;
                float v = acc[mt][nt][j] + b1[col];
                sA[row * LDA + col] = bfbits(fmaxf(v, 0.f));
            }
    for (int i = tid; i < 128 * 128; i += 256) {
        int c = i >> 7, n = i & 127;
        float wv = (n < 64) ? W2l[c * HID2 + n] : W2r[c * HID2 + (n - 64)];
        sB[n * LDA + c] = bfbits(wv);
    }
    __syncthreads();

    f32x4 acc2[2][8];
#pragma unroll
    for (int mt = 0; mt < 2; ++mt)
#pragma unroll
        for (int nt = 0; nt < 8; ++nt) acc2[mt][nt] = zero;

#pragma unroll
    for (int kt = 0; kt < 4; ++kt) {
        short8 a0 = *reinterpret_cast<const short8*>(&sA[(m0 + mr) * LDA + kt * 32 + q * 8]);
        short8 a1 = *reinterpret_cast<const short8*>(&sA[(m0 + 16 + mr) * LDA + kt * 32 + q * 8]);
#pragma unroll
        for (int nt = 0; nt < 8; ++nt) {
            short8 b = *reinterpret_cast<const short8*>(&sB[(nt * 16 + mr) * LDA + kt * 32 + q * 8]);
            acc2[0][nt] = __builtin_amdgcn_mfma_f32_16x16x32_bf16(a0, b, acc2[0][nt], 0, 0, 0);
            acc2[1][nt] = __builtin_amdgcn_mfma_f32_16x16x32_bf16(a1, b, acc2[1][nt], 0, 0, 0);
        }
    }
    __syncthreads(); // stage-2 LDS reads done; reuse sA/sB as output staging

    unsigned char* sG = (unsigned char*)sA;     // [128][64] fp8
    unsigned short* sS = (unsigned short*)sB;   // [128][64] bf16
#pragma unroll
    for (int mt = 0; mt < 2; ++mt)
#pragma unroll
        for (int nt = 0; nt < 8; ++nt)
#pragma unroll
            for (int j = 0; j < 4; ++j) {
                int row = m0 + mt * 16 + q * 4 + j;
                int col = nt * 16 + mr;
                float v = acc2[mt][nt][j];
                if (col < 64) sG[row * 64 + col] = f_to_fp8(v);
                else          sS[row * 64 + (col - 64)] = bfbits(v);
            }
    __syncthreads();
    const unsigned* sGu = (const unsigned*)sG;
    for (int i = tid; i < 128 * 16; i += 256) {
        int r = i >> 4, node = base + r;
        if (node < N) G8[(size_t)node * 16 + (i & 15)] = sGu[i];
    }
    const unsigned* sSu = (const unsigned*)sS;
    for (int i = tid; i < 128 * 32; i += 256) {
        int r = i >> 5, node = base + r;
        if (node < N) S2u[(size_t)node * 32 + (i & 31)] = sSu[i];
    }
}

// ---------------- gather-mean of G(fp8) + FC + sigmoid ----------------
// Same wide-load structure as agg1; epilogue fuses S2 + b2, ReLU, Wfc, sigmoid.
__global__ __launch_bounds__(256) void agg2fc_kernel(
    const unsigned* __restrict__ G8, const int* __restrict__ row_ptr,
    const int* __restrict__ srcs, const unsigned* __restrict__ S2u,
    const float* __restrict__ b2, const float* __restrict__ Wfc,
    const float* __restrict__ bfc, float* __restrict__ out, int N)
{
    int g = blockIdx.x * 256 + threadIdx.x;
    int node = g >> 6;
    if (node >= N) return;
    int lane = g & 63, el = lane >> 2, p = lane & 3;
    int s0 = row_ptr[node], s1 = row_ptr[node + 1];
    float a[16];
#pragma unroll
    for (int j = 0; j < 16; ++j) a[j] = 0.f;
    for (int e = s0; e < s1; e += 16) {
        int ek = e + el;
        bool valid = ek < s1;
        int src = srcs[valid ? ek : s0];
        uint4 u = ((const uint4*)(G8 + (size_t)src * 16))[p];
        if (valid) {
            f32x2 l0 = __builtin_amdgcn_cvt_pk_f32_fp8((int)u.x, false);
            f32x2 h0 = __builtin_amdgcn_cvt_pk_f32_fp8((int)u.x, true);
            f32x2 l1 = __builtin_amdgcn_cvt_pk_f32_fp8((int)u.y, false);
            f32x2 h1 = __builtin_amdgcn_cvt_pk_f32_fp8((int)u.y, true);
            f32x2 l2 = __builtin_amdgcn_cvt_pk_f32_fp8((int)u.z, false);
            f32x2 h2 = __builtin_amdgcn_cvt_pk_f32_fp8((int)u.z, true);
            f32x2 l3 = __builtin_amdgcn_cvt_pk_f32_fp8((int)u.w, false);
            f32x2 h3 = __builtin_amdgcn_cvt_pk_f32_fp8((int)u.w, true);
            a[0] += l0[0];  a[1] += l0[1];  a[2] += h0[0];  a[3] += h0[1];
            a[4] += l1[0];  a[5] += l1[1];  a[6] += h1[0];  a[7] += h1[1];
            a[8] += l2[0];  a[9] += l2[1];  a[10] += h2[0]; a[11] += h2[1];
            a[12] += l3[0]; a[13] += l3[1]; a[14] += h3[0]; a[15] += h3[1];
        }
    }
#pragma unroll
    for (int off = 4; off <= 32; off <<= 1)
#pragma unroll
        for (int j = 0; j < 16; ++j) a[j] += __shfl_xor(a[j], off);
    int deg = s1 - s0;
    float sc = deg > 0 ? 1.f / (float)deg : 0.f;
    // every lane computes its p-slice (features p*16..p*16+15); el-duplicates agree
    uint4 sa = ((const uint4*)(S2u + (size_t)node * 32))[2 * p];
    uint4 sb = ((const uint4*)(S2u + (size_t)node * 32))[2 * p + 1];
    float s2f[16] = {
        bflo(sa.x), bfhi(sa.x), bflo(sa.y), bfhi(sa.y),
        bflo(sa.z), bfhi(sa.z), bflo(sa.w), bfhi(sa.w),
        bflo(sb.x), bfhi(sb.x), bflo(sb.y), bfhi(sb.y),
        bflo(sb.z), bfhi(sb.z), bflo(sb.w), bfhi(sb.w)};
    const float4* b4 = (const float4*)(b2 + p * 16);
    const float4* w4 = (const float4*)(Wfc + p * 16);
    float z = 0.f;
#pragma unroll
    for (int qq = 0; qq < 4; ++qq) {
        float4 bq = b4[qq], wq = w4[qq];
        z += fmaxf(a[4 * qq + 0] * sc + s2f[4 * qq + 0] + bq.x, 0.f) * wq.x
           + fmaxf(a[4 * qq + 1] * sc + s2f[4 * qq + 1] + bq.y, 0.f) * wq.y
           + fmaxf(a[4 * qq + 2] * sc + s2f[4 * qq + 2] + bq.z, 0.f) * wq.z
           + fmaxf(a[4 * qq + 3] * sc + s2f[4 * qq + 3] + bq.w, 0.f) * wq.w;
    }
    z += __shfl_xor(z, 1);
    z += __shfl_xor(z, 2);
    if (lane == 0) out[node] = 1.f / (1.f + __expf(-(z + bfc[0])));
}

// ---------------- launch ----------------
static inline size_t align_up(size_t v, size_t a) { return (v + a - 1) & ~(a - 1); }

extern "C" void kernel_launch(void* const* d_in, const int* in_sizes, int n_in,
                              void* d_out, int out_size, void* d_ws, size_t ws_size,
                              hipStream_t stream) {
    const float* x   = (const float*)d_in[0];
    const int*   ei  = (const int*)d_in[1];
    const float* W1l = (const float*)d_in[2];
    const float* b1  = (const float*)d_in[3];
    const float* W1r = (const float*)d_in[4];
    const float* W2l = (const float*)d_in[5];
    const float* b2  = (const float*)d_in[6];
    const float* W2r = (const float*)d_in[7];
    const float* Wfc = (const float*)d_in[8];
    const float* bfc = (const float*)d_in[9];
    float* out = (float*)d_out;

    const int N = in_sizes[0] / IN_C;   // 100000
    const int E = in_sizes[1] / 2;      // 1600000
    const int NBUCK = (N + BR - 1) / BR;        // 196
    const int EPB = (E + P1B - 1) / P1B;        // 6250

    char* ws = (char*)d_ws;
    size_t o = 0;
    int* row_ptr  = (int*)(ws + o); o = align_up(o + (size_t)(N + 1) * 4, 256);
    int* srcs     = (int*)(ws + o); o = align_up(o + (size_t)E * 4, 256);
    int* cnt      = (int*)(ws + o); o = align_up(o + (size_t)P1B * 256 * 4, 256);
    int* gofs     = (int*)(ws + o); o = align_up(o + (size_t)P1B * 256 * 4, 256);
    int* bb       = (int*)(ws + o); o = align_up(o + 257 * 4, 256);
    // part (E*8 = 12.8 MB) aliases S2u (N*128 B = 12.8 MB): part dead after csr.
    size_t part_off = o;
    size_t sz1 = (size_t)E * 8, sz2 = (size_t)N * 128;
    o = align_up(part_off + (sz1 > sz2 ? sz1 : sz2), 256);
    int2* part = (int2*)(ws + part_off);
    unsigned* S2u = (unsigned*)(ws + part_off);
    unsigned* xf8 = (unsigned*)(ws + o); o = align_up(o + (size_t)N * 16 * 4, 256);
    unsigned* M1u = (unsigned*)(ws + o); o = align_up(o + (size_t)N * 32 * 4, 256);
    unsigned* G8  = (unsigned*)(ws + o); o = align_up(o + (size_t)N * 16 * 4, 256);

    count_kernel<<<P1B, 256, 0, stream>>>(ei, cnt, (const float4*)x, xf8,
                                          N * 16, E, EPB, NBUCK);
    offs_kernel<<<1, 256, 0, stream>>>(cnt, gofs, bb, row_ptr, N, E, NBUCK);
    scatter_kernel<<<P1B, 256, 0, stream>>>(ei, gofs, part, E, EPB, NBUCK);
    csr_kernel<<<NBUCK, 256, 0, stream>>>(part, bb, row_ptr, srcs, N);

    int gwb = (N * 64 + 255) / 256;
    agg1_kernel<<<gwb, 256, 0, stream>>>(xf8, row_ptr, srcs, M1u, N);
    dense_kernel<<<(N + 127) / 128, 256, 0, stream>>>(
        (const unsigned short*)M1u, x, W1l, b1, W1r, W2l, W2r, G8, S2u, N);
    agg2fc_kernel<<<gwb, 256, 0, stream>>>(G8, row_ptr, srcs, S2u, b2, Wfc, bfc, out, N);
}

// Round 9
// 329.815 us; speedup vs baseline: 4.6966x; 1.0806x over previous
//
#include <hip/hip_runtime.h>
#include <hip/hip_bf16.h>
#include <math.h>

// FraudGNN on MI355X. R6 structure restored (quarter-wave fp8 gathers at the
// ~1 line/cyc/XCD L2-miss service ceiling), with part[] packed to one dword
// (src<<9 | dst_local) to halve counting-sort traffic.

#define IN_C 64
#define HID 128
#define HID2 64
#define LDA 136     // LDS row stride for MFMA tiles
#define NBSHIFT 9   // 512 nodes per bucket
#define BR 512
#define P1B 256     // partition blocks (needs NBUCK <= 256: N <= 131072)

typedef short short8 __attribute__((ext_vector_type(8)));
typedef float f32x4 __attribute__((ext_vector_type(4)));
typedef float f32x2 __attribute__((ext_vector_type(2)));

__device__ inline unsigned short bfbits(float f) {
    __hip_bfloat16 h = __float2bfloat16(f);
    return *reinterpret_cast<unsigned short*>(&h);
}
__device__ inline float bflo(unsigned u) { return __uint_as_float(u << 16); }
__device__ inline float bfhi(unsigned u) { return __uint_as_float(u & 0xffff0000u); }
__device__ inline unsigned bfpack(float a, float b) {
    return ((unsigned)bfbits(b) << 16) | (unsigned)bfbits(a);
}
__device__ inline unsigned char f_to_fp8(float v) {
    return (unsigned char)(__builtin_amdgcn_cvt_pk_fp8_f32(v, v, 0, false) & 0xff);
}

// ---------------- CSR build: counting sort, bucket-contiguous ----------------
__global__ __launch_bounds__(256) void count_kernel(
    const int* __restrict__ ei, int* __restrict__ cnt,
    const float4* __restrict__ x4, unsigned* __restrict__ xf8,
    int n4, int E, int EPB, int NBUCK)
{
    __shared__ int hist[256];
    int t = threadIdx.x, j = blockIdx.x;
    hist[t] = 0;
    __syncthreads();
    int e0 = j * EPB, e1 = min(e0 + EPB, E);
    for (int e = e0 + t; e < e1; e += 256)
        atomicAdd(&hist[ei[E + e] >> NBSHIFT], 1);
    for (int i = j * 256 + t; i < n4; i += P1B * 256) {
        float4 f = x4[i];
        int lo = __builtin_amdgcn_cvt_pk_fp8_f32(f.x, f.y, 0, false);
        xf8[i] = (unsigned)__builtin_amdgcn_cvt_pk_fp8_f32(f.z, f.w, lo, true);
    }
    __syncthreads();
    if (t < NBUCK) cnt[j * NBUCK + t] = hist[t];
}

__global__ __launch_bounds__(256) void offs_kernel(
    const int* __restrict__ cnt, int* __restrict__ gofs,
    int* __restrict__ bucket_base, int* __restrict__ row_ptr,
    int N, int E, int NBUCK)
{
    __shared__ int tot[256];
    __shared__ int wred[4];
    int t = threadIdx.x, lane = t & 63, w = t >> 6;
    int run = 0;
    for (int j = 0; j < P1B; ++j)
        run += (t < NBUCK) ? cnt[j * NBUCK + t] : 0;
    tot[t] = run;
    __syncthreads();
    int v = tot[t];
    int x = v;
    for (int off = 1; off < 64; off <<= 1) {
        int u = __shfl_up(x, off);
        if (lane >= off) x += u;
    }
    if (lane == 63) wred[w] = x;
    __syncthreads();
    int add = 0;
    for (int k = 0; k < w; ++k) add += wred[k];
    int bb = x + add - v;
    if (t < NBUCK) bucket_base[t] = bb;
    if (t == 0) { bucket_base[NBUCK] = E; row_ptr[N] = E; }
    int run2 = bb;
    for (int j = 0; j < P1B; ++j) {
        if (t < NBUCK) {
            gofs[j * NBUCK + t] = run2;
            run2 += cnt[j * NBUCK + t];
        }
    }
}

// scatter packed record: (src << 9) | dst_local  (src < 2^17 = 131072 ok)
__global__ __launch_bounds__(256) void scatter_kernel(
    const int* __restrict__ ei, const int* __restrict__ gofs,
    int* __restrict__ part, int E, int EPB, int NBUCK)
{
    __shared__ int lofs[256];
    int t = threadIdx.x, j = blockIdx.x;
    lofs[t] = (t < NBUCK) ? gofs[j * NBUCK + t] : 0;
    __syncthreads();
    int e0 = j * EPB, e1 = min(e0 + EPB, E);
    for (int e = e0 + t; e < e1; e += 256) {
        int s = ei[e], d = ei[E + e];
        int b = d >> NBSHIFT;
        int p = atomicAdd(&lofs[b], 1);
        part[p] = (s << NBSHIFT) | (d & (BR - 1));
    }
}

__global__ __launch_bounds__(256) void csr_kernel(
    const int* __restrict__ part, const int* __restrict__ bucket_base,
    int* __restrict__ row_ptr, int* __restrict__ srcs, int N)
{
    __shared__ int ncnt[BR];
    __shared__ int nofs[BR];
    __shared__ int nfill[BR];
    __shared__ int wred[4];
    int b = blockIdx.x;
    int t = threadIdx.x, lane = t & 63, w = t >> 6;
    int node0 = b << NBSHIFT;
    int nn = min(BR, N - node0);
    int gb0 = bucket_base[b], gb1 = bucket_base[b + 1];
    ncnt[t] = 0; ncnt[t + 256] = 0;
    __syncthreads();
    for (int i = gb0 + t; i < gb1; i += 256)
        atomicAdd(&ncnt[part[i] & (BR - 1)], 1);
    __syncthreads();
    int c0 = ncnt[2 * t], c1 = ncnt[2 * t + 1];
    int v = c0 + c1;
    int x = v;
    for (int off = 1; off < 64; off <<= 1) {
        int u = __shfl_up(x, off);
        if (lane >= off) x += u;
    }
    if (lane == 63) wred[w] = x;
    __syncthreads();
    int add = 0;
    for (int k = 0; k < w; ++k) add += wred[k];
    int exc = x + add - v;
    nofs[2 * t] = exc;          nofs[2 * t + 1] = exc + c0;
    nfill[2 * t] = exc;         nfill[2 * t + 1] = exc + c0;
    __syncthreads();
    for (int i = t; i < nn; i += 256) row_ptr[node0 + i] = gb0 + nofs[i];
    for (int i = gb0 + t; i < gb1; i += 256) {
        int p = part[i];
        int pos = atomicAdd(&nfill[p & (BR - 1)], 1);
        srcs[gb0 + pos] = ((unsigned)p) >> NBSHIFT;
    }
}

// ---------------- gather-mean of x(fp8) -> M1 (bf16) ----------------
// Quarter-wave (16 lanes x 4B = 64B = 1 line) per edge; 4 edges per load inst.
__global__ __launch_bounds__(256) void agg1_kernel(
    const unsigned* __restrict__ xf8, const int* __restrict__ row_ptr,
    const int* __restrict__ srcs, unsigned* __restrict__ M1u, int N)
{
    int g = blockIdx.x * 256 + threadIdx.x;
    int node = g >> 6;
    if (node >= N) return;
    int lane = g & 63, ql = lane & 15, quarter = lane >> 4;
    int s0 = row_ptr[node], s1 = row_ptr[node + 1];
    float a0 = 0.f, a1 = 0.f, a2 = 0.f, a3 = 0.f;
    for (int e = s0; e < s1; e += 16) {
#pragma unroll
        for (int k = 0; k < 4; ++k) {
            int ek = e + quarter + 4 * k;
            bool valid = ek < s1;
            int src = srcs[valid ? ek : 0];
            unsigned u = xf8[(size_t)src * 16 + ql];
            if (valid) {
                f32x2 lo = __builtin_amdgcn_cvt_pk_f32_fp8((int)u, false);
                f32x2 hi = __builtin_amdgcn_cvt_pk_f32_fp8((int)u, true);
                a0 += lo[0]; a1 += lo[1]; a2 += hi[0]; a3 += hi[1];
            }
        }
    }
    a0 += __shfl_xor(a0, 16); a0 += __shfl_xor(a0, 32);
    a1 += __shfl_xor(a1, 16); a1 += __shfl_xor(a1, 32);
    a2 += __shfl_xor(a2, 16); a2 += __shfl_xor(a2, 32);
    a3 += __shfl_xor(a3, 16); a3 += __shfl_xor(a3, 32);
    int deg = s1 - s0;
    float scale = deg > 0 ? 1.f / (float)deg : 0.f;
    if (quarter == 0) {
        uint2 p;
        p.x = bfpack(a0 * scale, a1 * scale);
        p.y = bfpack(a2 * scale, a3 * scale);
        ((uint2*)M1u)[(size_t)node * 16 + ql] = p;
    }
}

// ---------------- fused dense: H1 -> G (fp8), S2 (bf16) ----------------
__global__ __launch_bounds__(256) void dense_kernel(
    const unsigned short* __restrict__ M1s, const float* __restrict__ x,
    const float* __restrict__ W1l, const float* __restrict__ b1,
    const float* __restrict__ W1r, const float* __restrict__ W2l,
    const float* __restrict__ W2r, unsigned* __restrict__ G8,
    unsigned* __restrict__ S2u, int N)
{
    __shared__ unsigned short sA[128 * LDA];
    __shared__ unsigned short sB[128 * LDA];
    int tid = threadIdx.x;
    int base = blockIdx.x * 128;

    for (int i = tid; i < 128 * 128; i += 256) {
        int k = i >> 7, n = i & 127;
        float wv = (k < 64) ? W1l[k * HID + n] : W1r[(k - 64) * HID + n];
        sB[n * LDA + k] = bfbits(wv);
    }
    for (int i = tid; i < 128 * 64; i += 256) {
        int r = i >> 6, c = i & 63;
        int node = min(base + r, N - 1);
        sA[r * LDA + c] = M1s[(size_t)node * 64 + c];
        sA[r * LDA + 64 + c] = bfbits(x[(size_t)node * 64 + c]);
    }
    __syncthreads();

    int w = tid >> 6, lane = tid & 63;
    int m0 = w * 32;
    int mr = lane & 15, q = lane >> 4;
    const f32x4 zero = {0.f, 0.f, 0.f, 0.f};

    f32x4 acc[2][8];
#pragma unroll
    for (int mt = 0; mt < 2; ++mt)
#pragma unroll
        for (int nt = 0; nt < 8; ++nt) acc[mt][nt] = zero;

#pragma unroll
    for (int kt = 0; kt < 4; ++kt) {
        short8 a0 = *reinterpret_cast<const short8*>(&sA[(m0 + mr) * LDA + kt * 32 + q * 8]);
        short8 a1 = *reinterpret_cast<const short8*>(&sA[(m0 + 16 + mr) * LDA + kt * 32 + q * 8]);
#pragma unroll
        for (int nt = 0; nt < 8; ++nt) {
            short8 b = *reinterpret_cast<const short8*>(&sB[(nt * 16 + mr) * LDA + kt * 32 + q * 8]);
            acc[0][nt] = __builtin_amdgcn_mfma_f32_16x16x32_bf16(a0, b, acc[0][nt], 0, 0, 0);
            acc[1][nt] = __builtin_amdgcn_mfma_f32_16x16x32_bf16(a1, b, acc[1][nt], 0, 0, 0);
        }
    }
    __syncthreads();

#pragma unroll
    for (int mt = 0; mt < 2; ++mt)
#pragma unroll
        for (int nt = 0; nt < 8; ++nt)
#pragma unroll
            for (int j = 0; j < 4; ++j) {
                int row = m0 + mt * 16 + q * 4 + j;
                int col = nt * 16 + mr;
                float v = acc[mt][nt][j] + b1[col];
                sA[row * LDA + col] = bfbits(fmaxf(v, 0.f));
            }
    for (int i = tid; i < 128 * 128; i += 256) {
        int c = i >> 7, n = i & 127;
        float wv = (n < 64) ? W2l[c * HID2 + n] : W2r[c * HID2 + (n - 64)];
        sB[n * LDA + c] = bfbits(wv);
    }
    __syncthreads();

    f32x4 acc2[2][8];
#pragma unroll
    for (int mt = 0; mt < 2; ++mt)
#pragma unroll
        for (int nt = 0; nt < 8; ++nt) acc2[mt][nt] = zero;

#pragma unroll
    for (int kt = 0; kt < 4; ++kt) {
        short8 a0 = *reinterpret_cast<const short8*>(&sA[(m0 + mr) * LDA + kt * 32 + q * 8]);
        short8 a1 = *reinterpret_cast<const short8*>(&sA[(m0 + 16 + mr) * LDA + kt * 32 + q * 8]);
#pragma unroll
        for (int nt = 0; nt < 8; ++nt) {
            short8 b = *reinterpret_cast<const short8*>(&sB[(nt * 16 + mr) * LDA + kt * 32 + q * 8]);
            acc2[0][nt] = __builtin_amdgcn_mfma_f32_16x16x32_bf16(a0, b, acc2[0][nt], 0, 0, 0);
            acc2[1][nt] = __builtin_amdgcn_mfma_f32_16x16x32_bf16(a1, b, acc2[1][nt], 0, 0, 0);
        }
    }
    __syncthreads(); // stage-2 LDS reads done; reuse sA/sB as output staging

    unsigned char* sG = (unsigned char*)sA;     // [128][64] fp8
    unsigned short* sS = (unsigned short*)sB;   // [128][64] bf16
#pragma unroll
    for (int mt = 0; mt < 2; ++mt)
#pragma unroll
        for (int nt = 0; nt < 8; ++nt)
#pragma unroll
            for (int j = 0; j < 4; ++j) {
                int row = m0 + mt * 16 + q * 4 + j;
                int col = nt * 16 + mr;
                float v = acc2[mt][nt][j];
                if (col < 64) sG[row * 64 + col] = f_to_fp8(v);
                else          sS[row * 64 + (col - 64)] = bfbits(v);
            }
    __syncthreads();
    const unsigned* sGu = (const unsigned*)sG;
    for (int i = tid; i < 128 * 16; i += 256) {
        int r = i >> 4, node = base + r;
        if (node < N) G8[(size_t)node * 16 + (i & 15)] = sGu[i];
    }
    const unsigned* sSu = (const unsigned*)sS;
    for (int i = tid; i < 128 * 32; i += 256) {
        int r = i >> 5, node = base + r;
        if (node < N) S2u[(size_t)node * 32 + (i & 31)] = sSu[i];
    }
}

// ---------------- gather-mean of G(fp8) + FC + sigmoid ----------------
__global__ __launch_bounds__(256) void agg2fc_kernel(
    const unsigned* __restrict__ G8, const int* __restrict__ row_ptr,
    const int* __restrict__ srcs, const unsigned* __restrict__ S2u,
    const float* __restrict__ b2, const float* __restrict__ Wfc,
    const float* __restrict__ bfc, float* __restrict__ out, int N)
{
    int g = blockIdx.x * 256 + threadIdx.x;
    int node = g >> 6;
    if (node >= N) return;
    int lane = g & 63, ql = lane & 15, quarter = lane >> 4;
    int s0 = row_ptr[node], s1 = row_ptr[node + 1];
    float a0 = 0.f, a1 = 0.f, a2 = 0.f, a3 = 0.f;
    for (int e = s0; e < s1; e += 16) {
#pragma unroll
        for (int k = 0; k < 4; ++k) {
            int ek = e + quarter + 4 * k;
            bool valid = ek < s1;
            int src = srcs[valid ? ek : 0];
            unsigned u = G8[(size_t)src * 16 + ql];
            if (valid) {
                f32x2 lo = __builtin_amdgcn_cvt_pk_f32_fp8((int)u, false);
                f32x2 hi = __builtin_amdgcn_cvt_pk_f32_fp8((int)u, true);
                a0 += lo[0]; a1 += lo[1]; a2 += hi[0]; a3 += hi[1];
            }
        }
    }
    a0 += __shfl_xor(a0, 16); a0 += __shfl_xor(a0, 32);
    a1 += __shfl_xor(a1, 16); a1 += __shfl_xor(a1, 32);
    a2 += __shfl_xor(a2, 16); a2 += __shfl_xor(a2, 32);
    a3 += __shfl_xor(a3, 16); a3 += __shfl_xor(a3, 32);
    int deg = s1 - s0;
    float scale = deg > 0 ? 1.f / (float)deg : 0.f;
    uint2 s2p = ((const uint2*)(S2u + (size_t)node * 32))[ql];
    float4 b4 = ((const float4*)b2)[ql];
    float4 w4 = ((const float4*)Wfc)[ql];
    float z = fmaxf(a0 * scale + bflo(s2p.x) + b4.x, 0.f) * w4.x
            + fmaxf(a1 * scale + bfhi(s2p.x) + b4.y, 0.f) * w4.y
            + fmaxf(a2 * scale + bflo(s2p.y) + b4.z, 0.f) * w4.z
            + fmaxf(a3 * scale + bfhi(s2p.y) + b4.w, 0.f) * w4.w;
    z += __shfl_xor(z, 1); z += __shfl_xor(z, 2);
    z += __shfl_xor(z, 4); z += __shfl_xor(z, 8);
    if (lane == 0) out[node] = 1.f / (1.f + __expf(-(z + bfc[0])));
}

// ---------------- launch ----------------
static inline size_t align_up(size_t v, size_t a) { return (v + a - 1) & ~(a - 1); }

extern "C" void kernel_launch(void* const* d_in, const int* in_sizes, int n_in,
                              void* d_out, int out_size, void* d_ws, size_t ws_size,
                              hipStream_t stream) {
    const float* x   = (const float*)d_in[0];
    const int*   ei  = (const int*)d_in[1];
    const float* W1l = (const float*)d_in[2];
    const float* b1  = (const float*)d_in[3];
    const float* W1r = (const float*)d_in[4];
    const float* W2l = (const float*)d_in[5];
    const float* b2  = (const float*)d_in[6];
    const float* W2r = (const float*)d_in[7];
    const float* Wfc = (const float*)d_in[8];
    const float* bfc = (const float*)d_in[9];
    float* out = (float*)d_out;

    const int N = in_sizes[0] / IN_C;   // 100000
    const int E = in_sizes[1] / 2;      // 1600000
    const int NBUCK = (N + BR - 1) / BR;        // 196
    const int EPB = (E + P1B - 1) / P1B;        // 6250

    char* ws = (char*)d_ws;
    size_t o = 0;
    int* row_ptr  = (int*)(ws + o); o = align_up(o + (size_t)(N + 1) * 4, 256);
    int* srcs     = (int*)(ws + o); o = align_up(o + (size_t)E * 4, 256);
    int* cnt      = (int*)(ws + o); o = align_up(o + (size_t)P1B * 256 * 4, 256);
    int* gofs     = (int*)(ws + o); o = align_up(o + (size_t)P1B * 256 * 4, 256);
    int* bb       = (int*)(ws + o); o = align_up(o + 257 * 4, 256);
    // part (E*4 = 6.4 MB) aliases S2u (N*128 B = 12.8 MB): part dead after csr.
    size_t part_off = o;
    size_t sz1 = (size_t)E * 4, sz2 = (size_t)N * 128;
    o = align_up(part_off + (sz1 > sz2 ? sz1 : sz2), 256);
    int* part = (int*)(ws + part_off);
    unsigned* S2u = (unsigned*)(ws + part_off);
    unsigned* xf8 = (unsigned*)(ws + o); o = align_up(o + (size_t)N * 16 * 4, 256);
    unsigned* M1u = (unsigned*)(ws + o); o = align_up(o + (size_t)N * 32 * 4, 256);
    unsigned* G8  = (unsigned*)(ws + o); o = align_up(o + (size_t)N * 16 * 4, 256);

    count_kernel<<<P1B, 256, 0, stream>>>(ei, cnt, (const float4*)x, xf8,
                                          N * 16, E, EPB, NBUCK);
    offs_kernel<<<1, 256, 0, stream>>>(cnt, gofs, bb, row_ptr, N, E, NBUCK);
    scatter_kernel<<<P1B, 256, 0, stream>>>(ei, gofs, part, E, EPB, NBUCK);
    csr_kernel<<<NBUCK, 256, 0, stream>>>(part, bb, row_ptr, srcs, N);

    int gwb = (N * 64 + 255) / 256;
    agg1_kernel<<<gwb, 256, 0, stream>>>(xf8, row_ptr, srcs, M1u, N);
    dense_kernel<<<(N + 127) / 128, 256, 0, stream>>>(
        (const unsigned short*)M1u, x, W1l, b1, W1r, W2l, W2r, G8, S2u, N);
    agg2fc_kernel<<<gwb, 256, 0, stream>>>(G8, row_ptr, srcs, S2u, b2, Wfc, bfc, out, N);
}

// Round 10
// 296.649 us; speedup vs baseline: 5.2217x; 1.1118x over previous
//
#include <hip/hip_runtime.h>
#include <hip/hip_bf16.h>
#include <math.h>

// FraudGNN on MI355X. Counting-sort CSR (count -> scatter[self-offs] -> csr),
// quarter-wave fp8 gathers (at ~87% of the per-XCD L2-miss line-service
// ceiling), fused MFMA dense kernel (H1 in LDS, G=H1@W2l pre-projected,
// S2=H1@W2r), FC+sigmoid fused into agg2fc. 6 kernels.

#define IN_C 64
#define HID 128
#define HID2 64
#define LDA 136     // LDS row stride for MFMA tiles
#define NBSHIFT 9   // 512 nodes per bucket
#define BR 512
#define P1B 256     // partition blocks (needs NBUCK <= 256: N <= 131072)

typedef short short8 __attribute__((ext_vector_type(8)));
typedef float f32x4 __attribute__((ext_vector_type(4)));
typedef float f32x2 __attribute__((ext_vector_type(2)));

__device__ inline unsigned short bfbits(float f) {
    __hip_bfloat16 h = __float2bfloat16(f);
    return *reinterpret_cast<unsigned short*>(&h);
}
__device__ inline float bflo(unsigned u) { return __uint_as_float(u << 16); }
__device__ inline float bfhi(unsigned u) { return __uint_as_float(u & 0xffff0000u); }
__device__ inline unsigned bfpack(float a, float b) {
    return ((unsigned)bfbits(b) << 16) | (unsigned)bfbits(a);
}
__device__ inline unsigned char f_to_fp8(float v) {
    return (unsigned char)(__builtin_amdgcn_cvt_pk_fp8_f32(v, v, 0, false) & 0xff);
}

// ---------------- k1: per-block bucket histogram + x->fp8 ----------------
__global__ __launch_bounds__(256) void count_kernel(
    const int* __restrict__ ei, int* __restrict__ cnt,
    const float4* __restrict__ x4, unsigned* __restrict__ xf8,
    int n4, int E, int EPB, int NBUCK)
{
    __shared__ int hist[256];
    int t = threadIdx.x, j = blockIdx.x;
    hist[t] = 0;
    __syncthreads();
    int e0 = j * EPB, e1 = min(e0 + EPB, E);
    for (int e = e0 + t; e < e1; e += 256)
        atomicAdd(&hist[ei[E + e] >> NBSHIFT], 1);
    for (int i = j * 256 + t; i < n4; i += P1B * 256) {
        float4 f = x4[i];
        int lo = __builtin_amdgcn_cvt_pk_fp8_f32(f.x, f.y, 0, false);
        xf8[i] = (unsigned)__builtin_amdgcn_cvt_pk_fp8_f32(f.z, f.w, lo, true);
    }
    __syncthreads();
    if (t < NBUCK) cnt[j * NBUCK + t] = hist[t];
}

// ---------------- k2: scatter with self-computed offsets ----------------
// Each block computes its own gofs column: bucket_base[b] + sum_{j'<j} cnt[j'][b].
// Block 0 publishes bucket_base. Packed record: (src << 9) | dst_local.
__global__ __launch_bounds__(256) void scatter_kernel(
    const int* __restrict__ ei, const int* __restrict__ cnt,
    int* __restrict__ bucket_base, int* __restrict__ row_ptr,
    int* __restrict__ part, int N, int E, int EPB, int NBUCK)
{
    __shared__ int tot[256];
    __shared__ int lofs[256];
    __shared__ int wred[4];
    int t = threadIdx.x, j = blockIdx.x;
    int lane = t & 63, w = t >> 6;
    // column sums: tot[b] (all blocks) and pre[b] (blocks j' < j)
    int pre = 0, total = 0;
    if (t < NBUCK) {
        for (int jj = 0; jj < P1B; ++jj) {       // coalesced across t per jj
            int c = cnt[jj * NBUCK + t];
            total += c;
            if (jj < j) pre += c;
        }
    }
    tot[t] = (t < NBUCK) ? total : 0;
    __syncthreads();
    // exclusive scan of tot -> bucket_base
    int v = tot[t];
    int x = v;
    for (int off = 1; off < 64; off <<= 1) {
        int u = __shfl_up(x, off);
        if (lane >= off) x += u;
    }
    if (lane == 63) wred[w] = x;
    __syncthreads();
    int add = 0;
    for (int k = 0; k < w; ++k) add += wred[k];
    int bb = x + add - v;
    lofs[t] = bb + pre;
    if (j == 0) {
        if (t < NBUCK) bucket_base[t] = bb;
        if (t == 0) { bucket_base[NBUCK] = E; row_ptr[N] = E; }
    }
    __syncthreads();
    int e0 = j * EPB, e1 = min(e0 + EPB, E);
    for (int e = e0 + t; e < e1; e += 256) {
        int s = ei[e], d = ei[E + e];
        int b = d >> NBSHIFT;
        int p = atomicAdd(&lofs[b], 1);
        part[p] = (s << NBSHIFT) | (d & (BR - 1));
    }
}

// ---------------- k3: per-bucket CSR (part is bucket-contiguous) ----------
__global__ __launch_bounds__(256) void csr_kernel(
    const int* __restrict__ part, const int* __restrict__ bucket_base,
    int* __restrict__ row_ptr, int* __restrict__ srcs, int N)
{
    __shared__ int ncnt[BR];
    __shared__ int nofs[BR];
    __shared__ int nfill[BR];
    __shared__ int wred[4];
    int b = blockIdx.x;
    int t = threadIdx.x, lane = t & 63, w = t >> 6;
    int node0 = b << NBSHIFT;
    int nn = min(BR, N - node0);
    int gb0 = bucket_base[b], gb1 = bucket_base[b + 1];
    ncnt[t] = 0; ncnt[t + 256] = 0;
    __syncthreads();
    for (int i = gb0 + t; i < gb1; i += 256)
        atomicAdd(&ncnt[part[i] & (BR - 1)], 1);
    __syncthreads();
    int c0 = ncnt[2 * t], c1 = ncnt[2 * t + 1];
    int v = c0 + c1;
    int x = v;
    for (int off = 1; off < 64; off <<= 1) {
        int u = __shfl_up(x, off);
        if (lane >= off) x += u;
    }
    if (lane == 63) wred[w] = x;
    __syncthreads();
    int add = 0;
    for (int k = 0; k < w; ++k) add += wred[k];
    int exc = x + add - v;
    nofs[2 * t] = exc;          nofs[2 * t + 1] = exc + c0;
    nfill[2 * t] = exc;         nfill[2 * t + 1] = exc + c0;
    __syncthreads();
    for (int i = t; i < nn; i += 256) row_ptr[node0 + i] = gb0 + nofs[i];
    for (int i = gb0 + t; i < gb1; i += 256) {
        int p = part[i];
        int pos = atomicAdd(&nfill[p & (BR - 1)], 1);
        srcs[gb0 + pos] = ((unsigned)p) >> NBSHIFT;
    }
}

// ---------------- k4: gather-mean of x(fp8) -> M1 (bf16) ----------------
// Quarter-wave (16 lanes x 4B = 64B = 1 line) per edge; 4 edges per load inst.
__global__ __launch_bounds__(256) void agg1_kernel(
    const unsigned* __restrict__ xf8, const int* __restrict__ row_ptr,
    const int* __restrict__ srcs, unsigned* __restrict__ M1u, int N)
{
    int g = blockIdx.x * 256 + threadIdx.x;
    int node = g >> 6;
    if (node >= N) return;
    int lane = g & 63, ql = lane & 15, quarter = lane >> 4;
    int s0 = row_ptr[node], s1 = row_ptr[node + 1];
    float a0 = 0.f, a1 = 0.f, a2 = 0.f, a3 = 0.f;
    for (int e = s0; e < s1; e += 16) {
#pragma unroll
        for (int k = 0; k < 4; ++k) {
            int ek = e + quarter + 4 * k;
            bool valid = ek < s1;
            int src = srcs[valid ? ek : 0];
            unsigned u = xf8[(size_t)src * 16 + ql];
            if (valid) {
                f32x2 lo = __builtin_amdgcn_cvt_pk_f32_fp8((int)u, false);
                f32x2 hi = __builtin_amdgcn_cvt_pk_f32_fp8((int)u, true);
                a0 += lo[0]; a1 += lo[1]; a2 += hi[0]; a3 += hi[1];
            }
        }
    }
    a0 += __shfl_xor(a0, 16); a0 += __shfl_xor(a0, 32);
    a1 += __shfl_xor(a1, 16); a1 += __shfl_xor(a1, 32);
    a2 += __shfl_xor(a2, 16); a2 += __shfl_xor(a2, 32);
    a3 += __shfl_xor(a3, 16); a3 += __shfl_xor(a3, 32);
    int deg = s1 - s0;
    float scale = deg > 0 ? 1.f / (float)deg : 0.f;
    if (quarter == 0) {
        uint2 p;
        p.x = bfpack(a0 * scale, a1 * scale);
        p.y = bfpack(a2 * scale, a3 * scale);
        ((uint2*)M1u)[(size_t)node * 16 + ql] = p;
    }
}

// ---------------- k5: fused dense: H1 -> G (fp8), S2 (bf16) ----------------
__global__ __launch_bounds__(256) void dense_kernel(
    const unsigned short* __restrict__ M1s, const float* __restrict__ x,
    const float* __restrict__ W1l, const float* __restrict__ b1,
    const float* __restrict__ W1r, const float* __restrict__ W2l,
    const float* __restrict__ W2r, unsigned* __restrict__ G8,
    unsigned* __restrict__ S2u, int N)
{
    __shared__ unsigned short sA[128 * LDA];
    __shared__ unsigned short sB[128 * LDA];
    int tid = threadIdx.x;
    int base = blockIdx.x * 128;

    for (int i = tid; i < 128 * 128; i += 256) {
        int k = i >> 7, n = i & 127;
        float wv = (k < 64) ? W1l[k * HID + n] : W1r[(k - 64) * HID + n];
        sB[n * LDA + k] = bfbits(wv);
    }
    for (int i = tid; i < 128 * 64; i += 256) {
        int r = i >> 6, c = i & 63;
        int node = min(base + r, N - 1);
        sA[r * LDA + c] = M1s[(size_t)node * 64 + c];
        sA[r * LDA + 64 + c] = bfbits(x[(size_t)node * 64 + c]);
    }
    __syncthreads();

    int w = tid >> 6, lane = tid & 63;
    int m0 = w * 32;
    int mr = lane & 15, q = lane >> 4;
    const f32x4 zero = {0.f, 0.f, 0.f, 0.f};

    f32x4 acc[2][8];
#pragma unroll
    for (int mt = 0; mt < 2; ++mt)
#pragma unroll
        for (int nt = 0; nt < 8; ++nt) acc[mt][nt] = zero;

#pragma unroll
    for (int kt = 0; kt < 4; ++kt) {
        short8 a0 = *reinterpret_cast<const short8*>(&sA[(m0 + mr) * LDA + kt * 32 + q * 8]);
        short8 a1 = *reinterpret_cast<const short8*>(&sA[(m0 + 16 + mr) * LDA + kt * 32 + q * 8]);
#pragma unroll
        for (int nt = 0; nt < 8; ++nt) {
            short8 b = *reinterpret_cast<const short8*>(&sB[(nt * 16 + mr) * LDA + kt * 32 + q * 8]);
            acc[0][nt] = __builtin_amdgcn_mfma_f32_16x16x32_bf16(a0, b, acc[0][nt], 0, 0, 0);
            acc[1][nt] = __builtin_amdgcn_mfma_f32_16x16x32_bf16(a1, b, acc[1][nt], 0, 0, 0);
        }
    }
    __syncthreads();

#pragma unroll
    for (int mt = 0; mt < 2; ++mt)
#pragma unroll
        for (int nt = 0; nt < 8; ++nt)
#pragma unroll
            for (int j = 0; j < 4; ++j) {
                int row = m0 + mt * 16 + q * 4 + j;
                int col = nt * 16 + mr;
                float v = acc[mt][nt][j] + b1[col];
                sA[row * LDA + col] = bfbits(fmaxf(v, 0.f));
            }
    for (int i = tid; i < 128 * 128; i += 256) {
        int c = i >> 7, n = i & 127;
        float wv = (n < 64) ? W2l[c * HID2 + n] : W2r[c * HID2 + (n - 64)];
        sB[n * LDA + c] = bfbits(wv);
    }
    __syncthreads();

    f32x4 acc2[2][8];
#pragma unroll
    for (int mt = 0; mt < 2; ++mt)
#pragma unroll
        for (int nt = 0; nt < 8; ++nt) acc2[mt][nt] = zero;

#pragma unroll
    for (int kt = 0; kt < 4; ++kt) {
        short8 a0 = *reinterpret_cast<const short8*>(&sA[(m0 + mr) * LDA + kt * 32 + q * 8]);
        short8 a1 = *reinterpret_cast<const short8*>(&sA[(m0 + 16 + mr) * LDA + kt * 32 + q * 8]);
#pragma unroll
        for (int nt = 0; nt < 8; ++nt) {
            short8 b = *reinterpret_cast<const short8*>(&sB[(nt * 16 + mr) * LDA + kt * 32 + q * 8]);
            acc2[0][nt] = __builtin_amdgcn_mfma_f32_16x16x32_bf16(a0, b, acc2[0][nt], 0, 0, 0);
            acc2[1][nt] = __builtin_amdgcn_mfma_f32_16x16x32_bf16(a1, b, acc2[1][nt], 0, 0, 0);
        }
    }
    __syncthreads(); // stage-2 LDS reads done; reuse sA/sB as output staging

    unsigned char* sG = (unsigned char*)sA;     // [128][64] fp8
    unsigned short* sS = (unsigned short*)sB;   // [128][64] bf16
#pragma unroll
    for (int mt = 0; mt < 2; ++mt)
#pragma unroll
        for (int nt = 0; nt < 8; ++nt)
#pragma unroll
            for (int j = 0; j < 4; ++j) {
                int row = m0 + mt * 16 + q * 4 + j;
                int col = nt * 16 + mr;
                float v = acc2[mt][nt][j];
                if (col < 64) sG[row * 64 + col] = f_to_fp8(v);
                else          sS[row * 64 + (col - 64)] = bfbits(v);
            }
    __syncthreads();
    const unsigned* sGu = (const unsigned*)sG;
    for (int i = tid; i < 128 * 16; i += 256) {
        int r = i >> 4, node = base + r;
        if (node < N) G8[(size_t)node * 16 + (i & 15)] = sGu[i];
    }
    const unsigned* sSu = (const unsigned*)sS;
    for (int i = tid; i < 128 * 32; i += 256) {
        int r = i >> 5, node = base + r;
        if (node < N) S2u[(size_t)node * 32 + (i & 31)] = sSu[i];
    }
}

// ---------------- k6: gather-mean of G(fp8) + FC + sigmoid ----------------
__global__ __launch_bounds__(256) void agg2fc_kernel(
    const unsigned* __restrict__ G8, const int* __restrict__ row_ptr,
    const int* __restrict__ srcs, const unsigned* __restrict__ S2u,
    const float* __restrict__ b2, const float* __restrict__ Wfc,
    const float* __restrict__ bfc, float* __restrict__ out, int N)
{
    int g = blockIdx.x * 256 + threadIdx.x;
    int node = g >> 6;
    if (node >= N) return;
    int lane = g & 63, ql = lane & 15, quarter = lane >> 4;
    int s0 = row_ptr[node], s1 = row_ptr[node + 1];
    float a0 = 0.f, a1 = 0.f, a2 = 0.f, a3 = 0.f;
    for (int e = s0; e < s1; e += 16) {
#pragma unroll
        for (int k = 0; k < 4; ++k) {
            int ek = e + quarter + 4 * k;
            bool valid = ek < s1;
            int src = srcs[valid ? ek : 0];
            unsigned u = G8[(size_t)src * 16 + ql];
            if (valid) {
                f32x2 lo = __builtin_amdgcn_cvt_pk_f32_fp8((int)u, false);
                f32x2 hi = __builtin_amdgcn_cvt_pk_f32_fp8((int)u, true);
                a0 += lo[0]; a1 += lo[1]; a2 += hi[0]; a3 += hi[1];
            }
        }
    }
    a0 += __shfl_xor(a0, 16); a0 += __shfl_xor(a0, 32);
    a1 += __shfl_xor(a1, 16); a1 += __shfl_xor(a1, 32);
    a2 += __shfl_xor(a2, 16); a2 += __shfl_xor(a2, 32);
    a3 += __shfl_xor(a3, 16); a3 += __shfl_xor(a3, 32);
    int deg = s1 - s0;
    float scale = deg > 0 ? 1.f / (float)deg : 0.f;
    uint2 s2p = ((const uint2*)(S2u + (size_t)node * 32))[ql];
    float4 b4 = ((const float4*)b2)[ql];
    float4 w4 = ((const float4*)Wfc)[ql];
    float z = fmaxf(a0 * scale + bflo(s2p.x) + b4.x, 0.f) * w4.x
            + fmaxf(a1 * scale + bfhi(s2p.x) + b4.y, 0.f) * w4.y
            + fmaxf(a2 * scale + bflo(s2p.y) + b4.z, 0.f) * w4.z
            + fmaxf(a3 * scale + bfhi(s2p.y) + b4.w, 0.f) * w4.w;
    z += __shfl_xor(z, 1); z += __shfl_xor(z, 2);
    z += __shfl_xor(z, 4); z += __shfl_xor(z, 8);
    if (lane == 0) out[node] = 1.f / (1.f + __expf(-(z + bfc[0])));
}

// ---------------- launch ----------------
static inline size_t align_up(size_t v, size_t a) { return (v + a - 1) & ~(a - 1); }

extern "C" void kernel_launch(void* const* d_in, const int* in_sizes, int n_in,
                              void* d_out, int out_size, void* d_ws, size_t ws_size,
                              hipStream_t stream) {
    const float* x   = (const float*)d_in[0];
    const int*   ei  = (const int*)d_in[1];
    const float* W1l = (const float*)d_in[2];
    const float* b1  = (const float*)d_in[3];
    const float* W1r = (const float*)d_in[4];
    const float* W2l = (const float*)d_in[5];
    const float* b2  = (const float*)d_in[6];
    const float* W2r = (const float*)d_in[7];
    const float* Wfc = (const float*)d_in[8];
    const float* bfc = (const float*)d_in[9];
    float* out = (float*)d_out;

    const int N = in_sizes[0] / IN_C;   // 100000
    const int E = in_sizes[1] / 2;      // 1600000
    const int NBUCK = (N + BR - 1) / BR;        // 196
    const int EPB = (E + P1B - 1) / P1B;        // 6250

    char* ws = (char*)d_ws;
    size_t o = 0;
    int* row_ptr  = (int*)(ws + o); o = align_up(o + (size_t)(N + 1) * 4, 256);
    int* srcs     = (int*)(ws + o); o = align_up(o + (size_t)E * 4, 256);
    int* cnt      = (int*)(ws + o); o = align_up(o + (size_t)P1B * 256 * 4, 256);
    int* bb       = (int*)(ws + o); o = align_up(o + 257 * 4, 256);
    // part (E*4 = 6.4 MB) aliases S2u (N*128 B = 12.8 MB): part dead after csr.
    size_t part_off = o;
    size_t sz1 = (size_t)E * 4, sz2 = (size_t)N * 128;
    o = align_up(part_off + (sz1 > sz2 ? sz1 : sz2), 256);
    int* part = (int*)(ws + part_off);
    unsigned* S2u = (unsigned*)(ws + part_off);
    unsigned* xf8 = (unsigned*)(ws + o); o = align_up(o + (size_t)N * 16 * 4, 256);
    unsigned* M1u = (unsigned*)(ws + o); o = align_up(o + (size_t)N * 32 * 4, 256);
    unsigned* G8  = (unsigned*)(ws + o); o = align_up(o + (size_t)N * 16 * 4, 256);

    count_kernel<<<P1B, 256, 0, stream>>>(ei, cnt, (const float4*)x, xf8,
                                          N * 16, E, EPB, NBUCK);
    scatter_kernel<<<P1B, 256, 0, stream>>>(ei, cnt, bb, row_ptr, part,
                                            N, E, EPB, NBUCK);
    csr_kernel<<<NBUCK, 256, 0, stream>>>(part, bb, row_ptr, srcs, N);

    int gwb = (N * 64 + 255) / 256;
    agg1_kernel<<<gwb, 256, 0, stream>>>(xf8, row_ptr, srcs, M1u, N);
    dense_kernel<<<(N + 127) / 128, 256, 0, stream>>>(
        (const unsigned short*)M1u, x, W1l, b1, W1r, W2l, W2r, G8, S2u, N);
    agg2fc_kernel<<<gwb, 256, 0, stream>>>(G8, row_ptr, srcs, S2u, b2, Wfc, bfc, out, N);
}